// Round 1
// baseline (249.380 us; speedup 1.0000x reference)
//
#include <hip/hip_runtime.h>
#include <hip/hip_bf16.h>

// BatchIrregularDownsample2d (D=2): out[b,c,j] = in[b,c,G[b,j]]
// G built from pooling_mask on the 128x128 subsampled grid (mask is constant
// per aligned 4x4 block; the reference samples it at stride 2).
//
// Fixed problem geometry (from reference): B=8, C=256, H=W=256 -> subgrid 128x128.
// N and M derived from in_sizes/out_size at launch.

#define HW_FULL 65536      // 256*256 mask pixels per batch
#define SUBDIM 128
#define SUBN   16384       // 128*128
#define T1     1024        // threads for index-build (16 entries each)
#define PER_T  16

__global__ __launch_bounds__(1024) void build_idx_kernel(
    const int* __restrict__ mask, int* __restrict__ hdr, int* __restrict__ gt, int M)
{
    const int b = blockIdx.x;
    const int t = threadIdx.x;
    const int* mb = mask + (long long)b * HW_FULL;

    // Pass 1: flags + local packed counts (16-bit fields: z, cs, dt, kl)
    unsigned char fl[PER_T];
    unsigned long long local = 0ULL;
    #pragma unroll
    for (int k = 0; k < PER_T; ++k) {
        int e = t * PER_T + k;          // row-major subgrid index
        int r = e >> 7;                 // subgrid row
        int c = e & 127;                // subgrid col
        int m = mb[(r << 9) + (c << 1)];  // full-res (2r, 2c)
        int z  = (m == 0);
        int cs = (m >= 1);
        int dt = (m == 1);
        int tl = ((r | c) & 1) == 0;    // top-left of 2x2 pool window
        int kl = (tl && (m >= 2)) ? 1 : 0;
        fl[k] = (unsigned char)(z | (cs << 1) | (dt << 2) | (kl << 3));
        local += (unsigned long long)z
               | ((unsigned long long)cs << 16)
               | ((unsigned long long)dt << 32)
               | ((unsigned long long)kl << 48);
    }

    // Block-wide inclusive scan over packed counters
    __shared__ unsigned long long sh[T1];
    sh[t] = local;
    __syncthreads();
    for (int off = 1; off < T1; off <<= 1) {
        unsigned long long v = (t >= off) ? sh[t - off] : 0ULL;
        __syncthreads();
        sh[t] += v;
        __syncthreads();
    }
    unsigned long long tot = sh[T1 - 1];
    unsigned long long ex  = (t > 0) ? sh[t - 1] : 0ULL;

    const int zt    = (int)( tot        & 0xFFFF);
    const int ndt   = (int)((tot >> 32) & 0xFFFF);
    const int nkl   = (int)((tot >> 48) & 0xFFFF);
    const int start = zt * 4;           // subgrid m==0 count * 4 == full-res count

    int csP = (int)((ex >> 16) & 0xFFFF);
    int dtP = (int)((ex >> 32) & 0xFFFF);
    int klP = (int)((ex >> 48) & 0xFFFF);

    // Pass 2: scatter tail gather-indices.
    // Tail layout: [0, ndt) dont-touch entries, [ndt, ndt+nkl) pooled reps.
    int* gtb = gt + (long long)b * M;
    #pragma unroll
    for (int k = 0; k < PER_T; ++k) {
        int f = fl[k];
        if (f & 4) { gtb[dtP]       = start + csP; ++dtP; }
        if (f & 8) { gtb[ndt + klP] = start + csP; ++klP; }
        if (f & 2) { ++csP; }
    }

    if (t == 0) {
        hdr[b * 4 + 0] = start;
        hdr[b * 4 + 1] = ndt;
        hdr[b * 4 + 2] = nkl;
        hdr[b * 4 + 3] = start + ndt + nkl;   // valid length
    }
}

__global__ void gather_kernel(const float* __restrict__ in,
                              const int* __restrict__ hdr,
                              const int* __restrict__ gt,
                              float* __restrict__ out,
                              int N, int M, int total)
{
    int o = blockIdx.x * blockDim.x + threadIdx.x;
    if (o >= total) return;
    unsigned int row = (unsigned int)o / (unsigned int)M;   // row = b*C + c
    int j = o - (int)(row * (unsigned int)M);
    int b = row >> 8;                                       // C = 256
    int start = hdr[b * 4 + 0];
    int len   = hdr[b * 4 + 3];
    float v = 0.0f;
    if (j < len) {
        int src = (j < start) ? j : gt[(long long)b * M + (j - start)];
        v = in[(long long)row * N + src];
    }
    out[o] = v;
}

extern "C" void kernel_launch(void* const* d_in, const int* in_sizes, int n_in,
                              void* d_out, int out_size, void* d_ws, size_t ws_size,
                              hipStream_t stream) {
    const float* x    = (const float*)d_in[0];
    const int*   mask = (const int*)d_in[1];
    float*       out  = (float*)d_out;

    const int B = in_sizes[1] / HW_FULL;          // 8
    const int C = 256;
    const int N = in_sizes[0] / (B * C);          // 32776
    const int M = out_size   / (B * C);           // 28681

    int* hdr = (int*)d_ws;                        // B*4 ints
    int* gt  = hdr + 32;                          // B*M ints (tail gather table)

    build_idx_kernel<<<B, T1, 0, stream>>>(mask, hdr, gt, M);

    const int total = out_size;
    const int threads = 256;
    const int blocks = (total + threads - 1) / threads;
    gather_kernel<<<blocks, threads, 0, stream>>>(x, hdr, gt, out, N, M, total);
}

// Round 2
// 159.142 us; speedup vs baseline: 1.5670x; 1.5670x over previous
//
#include <hip/hip_runtime.h>
#include <hip/hip_bf16.h>

// BatchIrregularDownsample2d (D=2): out[b,c,j] = in[b,c,G[b,j]]
// G built from pooling_mask on the 128x128 subsampled grid (mask is constant
// per aligned 4x4 block; the reference samples it at stride 2).
//
// R2: gather vectorized — 4 outputs/thread, aligned float4 stores, runtime
// division replaced by host-computed magic multiply.

#define HW_FULL 65536      // 256*256 mask pixels per batch
#define T1     1024        // threads for index-build (16 entries each)
#define PER_T  16

__global__ __launch_bounds__(1024) void build_idx_kernel(
    const int* __restrict__ mask, int* __restrict__ hdr, int* __restrict__ gt, int M)
{
    const int b = blockIdx.x;
    const int t = threadIdx.x;
    const int* mb = mask + (long long)b * HW_FULL;

    // Pass 1: flags + local packed counts (16-bit fields: z, cs, dt, kl)
    unsigned char fl[PER_T];
    unsigned long long local = 0ULL;
    #pragma unroll
    for (int k = 0; k < PER_T; ++k) {
        int e = t * PER_T + k;          // row-major subgrid index
        int r = e >> 7;                 // subgrid row
        int c = e & 127;                // subgrid col
        int m = mb[(r << 9) + (c << 1)];  // full-res (2r, 2c)
        int z  = (m == 0);
        int cs = (m >= 1);
        int dt = (m == 1);
        int tl = ((r | c) & 1) == 0;    // top-left of 2x2 pool window
        int kl = (tl && (m >= 2)) ? 1 : 0;
        fl[k] = (unsigned char)(z | (cs << 1) | (dt << 2) | (kl << 3));
        local += (unsigned long long)z
               | ((unsigned long long)cs << 16)
               | ((unsigned long long)dt << 32)
               | ((unsigned long long)kl << 48);
    }

    // Block-wide inclusive scan over packed counters
    __shared__ unsigned long long sh[T1];
    sh[t] = local;
    __syncthreads();
    for (int off = 1; off < T1; off <<= 1) {
        unsigned long long v = (t >= off) ? sh[t - off] : 0ULL;
        __syncthreads();
        sh[t] += v;
        __syncthreads();
    }
    unsigned long long tot = sh[T1 - 1];
    unsigned long long ex  = (t > 0) ? sh[t - 1] : 0ULL;

    const int zt    = (int)( tot        & 0xFFFF);
    const int ndt   = (int)((tot >> 32) & 0xFFFF);
    const int nkl   = (int)((tot >> 48) & 0xFFFF);
    const int start = zt * 4;           // subgrid m==0 count * 4 == full-res count

    int csP = (int)((ex >> 16) & 0xFFFF);
    int dtP = (int)((ex >> 32) & 0xFFFF);
    int klP = (int)((ex >> 48) & 0xFFFF);

    // Pass 2: scatter tail gather-indices.
    // Tail layout: [0, ndt) dont-touch entries, [ndt, ndt+nkl) pooled reps.
    int* gtb = gt + (long long)b * M;
    #pragma unroll
    for (int k = 0; k < PER_T; ++k) {
        int f = fl[k];
        if (f & 4) { gtb[dtP]       = start + csP; ++dtP; }
        if (f & 8) { gtb[ndt + klP] = start + csP; ++klP; }
        if (f & 2) { ++csP; }
    }

    if (t == 0) {
        hdr[b * 4 + 0] = start;
        hdr[b * 4 + 1] = ndt;
        hdr[b * 4 + 2] = nkl;
        hdr[b * 4 + 3] = start + ndt + nkl;   // valid length
    }
}

// 4 consecutive flat outputs per thread; aligned float4 store.
// row = o / M via magic multiply (exact: M * out_size < 2^RSHIFT).
__global__ void gather4_kernel(const float* __restrict__ in,
                               const int* __restrict__ hdr,
                               const int* __restrict__ gt,
                               float* __restrict__ out,
                               int N, int M, int cshift,
                               unsigned long long total,
                               unsigned long long magic, int rshift)
{
    unsigned long long q = (unsigned long long)blockIdx.x * blockDim.x + threadIdx.x;
    unsigned long long o = q << 2;
    if (o >= total) return;

    unsigned int row = (unsigned int)((o * magic) >> rshift);
    int j = (int)(o - (unsigned long long)row * (unsigned)M);

    float4 v;
    float* vf = reinterpret_cast<float*>(&v);

    if (j + 3 < M && o + 3 < total) {
        // whole quad in one row
        int b     = row >> cshift;
        int start = hdr[b * 4 + 0];
        int len   = hdr[b * 4 + 3];
        const float* rin = in + (unsigned long long)row * (unsigned)N;
        const int*   gtb = gt + (unsigned long long)b * (unsigned)M - start;  // gtb[j] valid for j>=start
        #pragma unroll
        for (int k = 0; k < 4; ++k) {
            int jj = j + k;
            float x = 0.0f;
            if (jj < len) x = rin[(jj < start) ? jj : gtb[jj]];
            vf[k] = x;
        }
        *reinterpret_cast<float4*>(out + o) = v;
    } else {
        // row-boundary or buffer-end quad: per-element
        #pragma unroll
        for (int k = 0; k < 4; ++k) {
            unsigned long long ok = o + k;
            if (ok >= total) break;
            unsigned int r2 = (unsigned int)((ok * magic) >> rshift);
            int j2 = (int)(ok - (unsigned long long)r2 * (unsigned)M);
            int b2 = r2 >> cshift;
            int s2 = hdr[b2 * 4 + 0];
            int l2 = hdr[b2 * 4 + 3];
            float x = 0.0f;
            if (j2 < l2) {
                int src = (j2 < s2) ? j2 : gt[(unsigned long long)b2 * (unsigned)M + (j2 - s2)];
                x = in[(unsigned long long)r2 * (unsigned)N + src];
            }
            out[ok] = x;
        }
    }
}

extern "C" void kernel_launch(void* const* d_in, const int* in_sizes, int n_in,
                              void* d_out, int out_size, void* d_ws, size_t ws_size,
                              hipStream_t stream) {
    const float* x    = (const float*)d_in[0];
    const int*   mask = (const int*)d_in[1];
    float*       out  = (float*)d_out;

    const int B = in_sizes[1] / HW_FULL;          // 8
    const int C = 256;
    const int N = in_sizes[0] / (B * C);          // 32776
    const int M = out_size   / (B * C);           // 28681

    int cshift = 0;                               // log2(C)
    while ((1 << cshift) < C) ++cshift;

    // magic multiply for division by M: exact for o < total when M*total < 2^F
    int rshift = 40;
    while ((unsigned long long)M * (unsigned long long)out_size >= (1ULL << rshift)) ++rshift;
    unsigned long long magic = ((1ULL << rshift) / (unsigned)M) + 1;

    int* hdr = (int*)d_ws;                        // B*4 ints
    int* gt  = hdr + 32;                          // B*M ints (tail gather table)

    build_idx_kernel<<<B, T1, 0, stream>>>(mask, hdr, gt, M);

    const unsigned long long total = (unsigned long long)out_size;
    const unsigned long long nquads = (total + 3) >> 2;
    const int threads = 256;
    const unsigned long long blocks = (nquads + threads - 1) / threads;
    gather4_kernel<<<(unsigned int)blocks, threads, 0, stream>>>(
        x, hdr, gt, out, N, M, cshift, total, magic, rshift);
}

// Round 3
// 112.378 us; speedup vs baseline: 2.2191x; 1.4161x over previous
//
#include <hip/hip_runtime.h>
#include <hip/hip_bf16.h>

// BatchIrregularDownsample2d (D=2): out[b,c,j] = in[b,c,G[b,j]]
// R3: flat-aligned float4 stores + per-lane contiguous (unaligned-capable)
// 16B loads for the prefix region and for the gather-index table.

#define HW_FULL 65536      // 256*256 mask pixels per batch
#define T1     1024
#define PER_T  16

typedef float f4a __attribute__((ext_vector_type(4), aligned(4)));
typedef int   i4a __attribute__((ext_vector_type(4), aligned(4)));

__global__ __launch_bounds__(1024) void build_idx_kernel(
    const int* __restrict__ mask, int* __restrict__ hdr, int* __restrict__ gt, int M)
{
    const int b = blockIdx.x;
    const int t = threadIdx.x;
    const int* mb = mask + (long long)b * HW_FULL;

    unsigned char fl[PER_T];
    unsigned long long local = 0ULL;
    #pragma unroll
    for (int k = 0; k < PER_T; ++k) {
        int e = t * PER_T + k;
        int r = e >> 7;
        int c = e & 127;
        int m = mb[(r << 9) + (c << 1)];
        int z  = (m == 0);
        int cs = (m >= 1);
        int dt = (m == 1);
        int tl = ((r | c) & 1) == 0;
        int kl = (tl && (m >= 2)) ? 1 : 0;
        fl[k] = (unsigned char)(z | (cs << 1) | (dt << 2) | (kl << 3));
        local += (unsigned long long)z
               | ((unsigned long long)cs << 16)
               | ((unsigned long long)dt << 32)
               | ((unsigned long long)kl << 48);
    }

    __shared__ unsigned long long sh[T1];
    sh[t] = local;
    __syncthreads();
    for (int off = 1; off < T1; off <<= 1) {
        unsigned long long v = (t >= off) ? sh[t - off] : 0ULL;
        __syncthreads();
        sh[t] += v;
        __syncthreads();
    }
    unsigned long long tot = sh[T1 - 1];
    unsigned long long ex  = (t > 0) ? sh[t - 1] : 0ULL;

    const int zt    = (int)( tot        & 0xFFFF);
    const int ndt   = (int)((tot >> 32) & 0xFFFF);
    const int nkl   = (int)((tot >> 48) & 0xFFFF);
    const int start = zt * 4;

    int csP = (int)((ex >> 16) & 0xFFFF);
    int dtP = (int)((ex >> 32) & 0xFFFF);
    int klP = (int)((ex >> 48) & 0xFFFF);

    int* gtb = gt + (long long)b * M;
    #pragma unroll
    for (int k = 0; k < PER_T; ++k) {
        int f = fl[k];
        if (f & 4) { gtb[dtP]       = start + csP; ++dtP; }
        if (f & 8) { gtb[ndt + klP] = start + csP; ++klP; }
        if (f & 2) { ++csP; }
    }

    if (t == 0) {
        hdr[b * 4 + 0] = start;
        hdr[b * 4 + 1] = ndt;
        hdr[b * 4 + 2] = nkl;
        hdr[b * 4 + 3] = start + ndt + nkl;
    }
}

// One aligned output float4 per thread. Loads are per-lane contiguous 16B
// (unaligned-capable) so both sides of the copy are coalesced.
__global__ void gather4_kernel(const float* __restrict__ in,
                               const int* __restrict__ hdr,
                               const int* __restrict__ gt,
                               float* __restrict__ out,
                               int N, int M, int cshift,
                               unsigned long long total,
                               unsigned long long magic, int rshift)
{
    unsigned long long q = (unsigned long long)blockIdx.x * blockDim.x + threadIdx.x;
    unsigned long long o = q << 2;
    if (o >= total) return;

    unsigned int row = (unsigned int)((o * magic) >> rshift);
    int j = (int)(o - (unsigned long long)row * (unsigned)M);

    if (j + 3 < M && o + 3 < total) {
        int b     = row >> cshift;
        int start = hdr[b * 4 + 0];
        int len   = hdr[b * 4 + 3];
        const float* rin = in + (unsigned long long)row * (unsigned)N;

        float4 v;
        if (j + 3 < start) {
            // prefix: contiguous copy, per-lane 16B load
            f4a lv = *reinterpret_cast<const f4a*>(rin + j);
            v = make_float4(lv.x, lv.y, lv.z, lv.w);
        } else if (j >= start && j + 3 < len) {
            // tail: 16B index load + 4 scalar gathers (indices monotonic)
            const int* gtb = gt + (unsigned long long)b * (unsigned)M;
            i4a idx = *reinterpret_cast<const i4a*>(gtb + (j - start));
            v = make_float4(rin[idx.x], rin[idx.y], rin[idx.z], rin[idx.w]);
        } else {
            // straddles start or len: per-element
            const int* gtb = gt + (unsigned long long)b * (unsigned)M - start;
            float* vf = reinterpret_cast<float*>(&v);
            #pragma unroll
            for (int k = 0; k < 4; ++k) {
                int jj = j + k;
                float x = 0.0f;
                if (jj < len) x = rin[(jj < start) ? jj : gtb[jj]];
                vf[k] = x;
            }
        }
        *reinterpret_cast<float4*>(out + o) = v;
    } else {
        // row-boundary or buffer-end quad: per-element
        #pragma unroll
        for (int k = 0; k < 4; ++k) {
            unsigned long long ok = o + k;
            if (ok >= total) break;
            unsigned int r2 = (unsigned int)((ok * magic) >> rshift);
            int j2 = (int)(ok - (unsigned long long)r2 * (unsigned)M);
            int b2 = r2 >> cshift;
            int s2 = hdr[b2 * 4 + 0];
            int l2 = hdr[b2 * 4 + 3];
            float x = 0.0f;
            if (j2 < l2) {
                int src = (j2 < s2) ? j2 : gt[(unsigned long long)b2 * (unsigned)M + (j2 - s2)];
                x = in[(unsigned long long)r2 * (unsigned)N + src];
            }
            out[ok] = x;
        }
    }
}

extern "C" void kernel_launch(void* const* d_in, const int* in_sizes, int n_in,
                              void* d_out, int out_size, void* d_ws, size_t ws_size,
                              hipStream_t stream) {
    const float* x    = (const float*)d_in[0];
    const int*   mask = (const int*)d_in[1];
    float*       out  = (float*)d_out;

    const int B = in_sizes[1] / HW_FULL;          // 8
    const int C = 256;
    const int N = in_sizes[0] / (B * C);          // 32776
    const int M = out_size   / (B * C);           // 28681

    int cshift = 0;
    while ((1 << cshift) < C) ++cshift;

    int rshift = 40;
    while ((unsigned long long)M * (unsigned long long)out_size >= (1ULL << rshift)) ++rshift;
    unsigned long long magic = ((1ULL << rshift) / (unsigned)M) + 1;

    int* hdr = (int*)d_ws;                        // B*4 ints
    int* gt  = hdr + 32;                          // B*M ints

    build_idx_kernel<<<B, T1, 0, stream>>>(mask, hdr, gt, M);

    const unsigned long long total = (unsigned long long)out_size;
    const unsigned long long nquads = (total + 3) >> 2;
    const int threads = 256;
    const unsigned long long blocks = (nquads + threads - 1) / threads;
    gather4_kernel<<<(unsigned int)blocks, threads, 0, stream>>>(
        x, hdr, gt, out, N, M, cshift, total, magic, rshift);
}